// Round 15
// baseline (255.275 us; speedup 1.0000x reference)
//
#include <hip/hip_runtime.h>

// Problem constants
#define NT 64
#define NF 1024
#define NB 1024
#define ND 2048
#define NTP 32
#define NN2 (NT * NTP)
#define NP 27
#define NW2ROW 1027
#define BK 64
#define BM 64
#define BN 64

// MEASUREMENT: idempotent rep loops so each kernel's single dispatch exceeds
// the ~42us ws-poison fills and surfaces in rocprof top-5 with counters.
#define REP_PREP 12
#define REP_FUSED 6
#define REP_FIN 24

typedef __attribute__((ext_vector_type(8))) short short8;
typedef __attribute__((ext_vector_type(4))) float f32x4;

static __device__ __forceinline__ unsigned short f2bf(float x) {
    unsigned u = __float_as_uint(x);
    unsigned r = (u + 0x7FFFu + ((u >> 16) & 1u)) >> 16;   // RNE
    return (unsigned short)r;
}

// ---------------------------------------------------------------------------
// prep v5 (j-range split), rep'd. Grid 640 x 1024.
// ---------------------------------------------------------------------------
__global__ __launch_bounds__(1024) void prep_kernel(
    const int* __restrict__ idx, const float* __restrict__ w_clc,
    const float* __restrict__ w1, const float* __restrict__ w2,
    const float* __restrict__ d, unsigned short* __restrict__ Wf,
    unsigned short* __restrict__ db)
{
    __shared__ __align__(16) float tile[21 * 256];   // 21,504 B
    int bid = blockIdx.x;
    int tid = threadIdx.x;

#pragma unroll 1
    for (int rep = 0; rep < REP_PREP; ++rep) {
        if (bid < 512) {
            int t = bid >> 3, je = bid & 7;

            float4* tz = (float4*)tile;
            for (int i = tid; i < 1344; i += 1024) tz[i] = make_float4(0, 0, 0, 0);
            __syncthreads();

            {
                int f = tid;
                int j = idx[t * NF + f];
                if ((j >> 8) == je) {
                    int jl = j & 255;
                    float2 a = *(const float2*)&w_clc[(size_t)(t * NF + f) * 2];
                    atomicAdd(&tile[0 * 256 + jl], a.x);
                    atomicAdd(&tile[1 * 256 + jl], a.y);
                    const float* p1 = &w1[(size_t)(t * NF + f) * 3];
                    atomicAdd(&tile[2 * 256 + jl], p1[0]);
                    atomicAdd(&tile[3 * 256 + jl], p1[1]);
                    atomicAdd(&tile[4 * 256 + jl], p1[2]);
                    const float* w2row = &w2[((size_t)t * NW2ROW + f) * 16];
                    float4 q0 = *(const float4*)&w2row[0];
                    float4 q1 = *(const float4*)&w2row[4];
                    float4 q2 = *(const float4*)&w2row[8];
                    float4 q3 = *(const float4*)&w2row[12];
                    atomicAdd(&tile[ 5 * 256 + jl], q0.x);
                    atomicAdd(&tile[ 6 * 256 + jl], q0.y);
                    atomicAdd(&tile[ 7 * 256 + jl], q0.z);
                    atomicAdd(&tile[ 8 * 256 + jl], q0.w);
                    atomicAdd(&tile[ 9 * 256 + jl], q1.x);
                    atomicAdd(&tile[10 * 256 + jl], q1.y);
                    atomicAdd(&tile[11 * 256 + jl], q1.z);
                    atomicAdd(&tile[12 * 256 + jl], q1.w);
                    atomicAdd(&tile[13 * 256 + jl], q2.x);
                    atomicAdd(&tile[14 * 256 + jl], q2.y);
                    atomicAdd(&tile[15 * 256 + jl], q2.z);
                    atomicAdd(&tile[16 * 256 + jl], q2.w);
                    atomicAdd(&tile[17 * 256 + jl], q3.x);
                    atomicAdd(&tile[18 * 256 + jl], q3.y);
                    atomicAdd(&tile[19 * 256 + jl], q3.z);
                    atomicAdd(&tile[20 * 256 + jl], q3.w);
                }
            }
            __syncthreads();

            for (int i = tid; i < 672; i += 1024) {
                int c = i >> 5, off = (i & 31) * 8;
                const float* tr = &tile[c * 256 + off];
                union { unsigned short u[8]; uint4 v; } pk;
#pragma unroll
                for (int e = 0; e < 8; ++e) pk.u[e] = f2bf(tr[e]);
                *(uint4*)&Wf[(size_t)(t * NTP + c) * ND + je * 256 + off] = pk.v;
            }
            uint4 z = make_uint4(0, 0, 0, 0);
            for (int i = tid; i < 352; i += 1024) {
                int c = 21 + (i >> 5), off = (i & 31) * 8;
                *(uint4*)&Wf[(size_t)(t * NTP + c) * ND + je * 256 + off] = z;
            }
            __syncthreads();   // tile reused next rep
        } else {
            int cb = bid - 512;
            int i16 = (cb * 1024 + tid) * 16;
#pragma unroll
            for (int h = 0; h < 2; ++h) {
                int i8 = i16 + h * 8;
                float4 a = *(const float4*)&d[i8];
                float4 b = *(const float4*)&d[i8 + 4];
                union { unsigned short u[8]; uint4 v; } pk;
                pk.u[0] = f2bf(a.x); pk.u[1] = f2bf(a.y); pk.u[2] = f2bf(a.z); pk.u[3] = f2bf(a.w);
                pk.u[4] = f2bf(b.x); pk.u[5] = f2bf(b.y); pk.u[6] = f2bf(b.z); pk.u[7] = f2bf(b.w);
                *(uint4*)&db[i8] = pk.v;
            }
        }
    }
}

// ---------------------------------------------------------------------------
// Fused GEMM + epilogue (R14 structure), rep'd, no early returns.
// ---------------------------------------------------------------------------
__global__ __launch_bounds__(256, 2) void fused_kernel(
    const unsigned short* __restrict__ A,
    const unsigned short* __restrict__ Bm,
    const float* __restrict__ b_clc, const float* __restrict__ b1,
    const float* __restrict__ b2, const float* __restrict__ w2,
    const int* __restrict__ cc, float* __restrict__ ptl2)
{
    __shared__ __align__(16) char smem[32768];
    unsigned short (*As)[BM][BK] = (unsigned short(*)[BM][BK])smem;
    unsigned short (*Bs)[BN][BK] = (unsigned short(*)[BN][BK])(smem + 16384);
    float* Cl  = (float*)smem;
    float* red = (float*)(smem + 16896);

    int tid = threadIdx.x;
    int lane = tid & 63;
    int wv = tid >> 6;
    int wr = wv & 1;
    int wq = wv >> 1;
    int nb = blockIdx.x;
    int mb = blockIdx.y;
    int m0 = mb * BM;
    int n0 = nb * BN;
    int r0 = lane & 15;
    int kq = lane >> 4;
    int sx = r0 & 7;
    int sl0 = ((0 * 4 + kq) ^ sx) * 8;
    int sl1 = ((1 * 4 + kq) ^ sx) * 8;

#define STAGE(buf, kt)                                                          \
    {                                                                           \
        size_t koff = (size_t)(kt) * BK;                                        \
        _Pragma("unroll")                                                       \
        for (int p = 0; p < 2; ++p) {                                           \
            int chunk = p * 256 + tid;                                          \
            int row = chunk >> 3, c = chunk & 7;                                \
            int csw = (c ^ (row & 7)) * 8;                                      \
            const unsigned short* ga = A + (size_t)(m0 + row) * ND + koff + csw;\
            __builtin_amdgcn_global_load_lds(                                   \
                (const __attribute__((address_space(1))) void*)ga,              \
                (__attribute__((address_space(3))) void*)&As[buf][row][c * 8],  \
                16, 0, 0);                                                      \
        }                                                                       \
        _Pragma("unroll")                                                       \
        for (int p = 0; p < 2; ++p) {                                           \
            int chunk = p * 256 + tid;                                          \
            int row = chunk >> 3, c = chunk & 7;                                \
            int csw = (c ^ (row & 7)) * 8;                                      \
            const unsigned short* gb = Bm + (size_t)(n0 + row) * ND + koff + csw;\
            __builtin_amdgcn_global_load_lds(                                   \
                (const __attribute__((address_space(1))) void*)gb,              \
                (__attribute__((address_space(3))) void*)&Bs[buf][row][c * 8],  \
                16, 0, 0);                                                      \
        }                                                                       \
    }

#pragma unroll 1
    for (int rep = 0; rep < REP_FUSED; ++rep) {
        f32x4 acc[2][2];
#pragma unroll
        for (int mi = 0; mi < 2; ++mi)
#pragma unroll
            for (int ni = 0; ni < 2; ++ni) acc[mi][ni] = (f32x4)0.f;

        STAGE(0, 0);
        __syncthreads();

        int cur = 0;
        for (int kt = 0; kt < 32; ++kt) {
            if (kt < 31) STAGE(cur ^ 1, kt + 1);

            short8 af[2][2], bf[2][2];
#pragma unroll
            for (int mi = 0; mi < 2; ++mi) {
                af[mi][0] = *(const short8*)&As[cur][wr*32 + mi*16 + r0][sl0];
                af[mi][1] = *(const short8*)&As[cur][wr*32 + mi*16 + r0][sl1];
            }
#pragma unroll
            for (int ni = 0; ni < 2; ++ni) {
                bf[ni][0] = *(const short8*)&Bs[cur][wq*32 + ni*16 + r0][sl0];
                bf[ni][1] = *(const short8*)&Bs[cur][wq*32 + ni*16 + r0][sl1];
            }
#pragma unroll
            for (int ks = 0; ks < 2; ++ks)
#pragma unroll
                for (int mi = 0; mi < 2; ++mi)
#pragma unroll
                    for (int ni = 0; ni < 2; ++ni)
                        acc[mi][ni] = __builtin_amdgcn_mfma_f32_16x16x32_bf16(
                            af[mi][ks], bf[ni][ks], acc[mi][ni], 0, 0, 0);
            __syncthreads();
            cur ^= 1;
        }

#pragma unroll
        for (int mi = 0; mi < 2; ++mi)
#pragma unroll
            for (int ni = 0; ni < 2; ++ni) {
                int n = wq * 32 + ni * 16 + r0;
                int bl = wr * 32 + mi * 16 + kq * 4;
#pragma unroll
                for (int q = 0; q < 4; ++q)
                    Cl[(bl + q) * 65 + n] = acc[mi][ni][q];
            }
        __syncthreads();

        int tl = tid >> 6;
        int bl = lane;
        float s[NP];
#pragma unroll
        for (int k = 0; k < NP; ++k) s[k] = 0.f;

        if (tl < 2) {
            int t = nb * 2 + tl;

            float a21[21];
#pragma unroll
            for (int k = 0; k < 21; ++k) a21[k] = Cl[bl * 65 + tl * 32 + k];

            float L0 = a21[0] + b_clc[t * 2 + 0];
            float L1 = a21[1] + b_clc[t * 2 + 1];
            float mm = fmaxf(L0, L1);
            float e0 = __expf(L0 - mm), e1 = __expf(L1 - mm);
            float gate = e1 / (e0 + e1);

            float l1v[3];
            float m1 = -3.0e38f;
#pragma unroll
            for (int c = 0; c < 3; ++c) {
                l1v[c] = a21[2 + c] + b1[t * 3 + c];
                m1 = fmaxf(m1, l1v[c]);
            }
            float p1[3]; float S1 = 0.f;
#pragma unroll
            for (int c = 0; c < 3; ++c) { p1[c] = __expf(l1v[c] - m1); S1 += p1[c]; }
            float invS1g = gate / S1;

            float r0f = fmaxf(l1v[0], 0.f);
            float r1f = fmaxf(l1v[1], 0.f);
            float r2f = fmaxf(l1v[2], 0.f);

            const float* w2t = w2 + ((size_t)t * NW2ROW + NF) * 16;
            float l2[16]; float m2 = -3.0e38f;
#pragma unroll
            for (int nn = 0; nn < 16; ++nn) {
                float v = a21[5 + nn] + b2[t * 16 + nn];
                v = fmaf(r0f, w2t[nn], v);
                v = fmaf(r1f, w2t[16 + nn], v);
                v = fmaf(r2f, w2t[32 + nn], v);
                l2[nn] = v;
                m2 = fmaxf(m2, v);
            }
            float S2 = 0.f; float p2[16];
#pragma unroll
            for (int nn = 0; nn < 16; ++nn) { p2[nn] = __expf(l2[nn] - m2); S2 += p2[nn]; }
            float invS2g = gate * __frcp_rn(S2);

#pragma unroll
            for (int c = 0; c < 3; ++c) {
                int sl = cc[t * 3 + c];
                float pc = p1[c] * invS1g;
#pragma unroll
                for (int x = 0; x < 5; ++x) {
                    if (sl == x) { s[x] += pc; s[5 + x] += gate; }
                }
            }
#pragma unroll
            for (int nn = 0; nn < 16; ++nn) s[10 + nn] += p2[nn] * invS2g;
            s[26] += gate;
        }

        if (tl == 1) {
#pragma unroll
            for (int k = 0; k < NP; ++k) red[k * 64 + bl] = s[k];
        }
        __syncthreads();
        if (tl == 0) {
#pragma unroll
            for (int k = 0; k < NP; ++k) s[k] += red[k * 64 + bl];
            float* pt = ptl2 + (size_t)nb * NP * NB + m0 + bl;
#pragma unroll
            for (int k = 0; k < NP; ++k)
                pt[(size_t)k * NB] = s[k];
        }
        __syncthreads();
    }
#undef STAGE
}

// ---------------------------------------------------------------------------
// Finalize (R14 structure), rep'd, no early returns.
// ---------------------------------------------------------------------------
__global__ __launch_bounds__(1024) void finalize_kernel(
    const float* __restrict__ ptl2, float* __restrict__ out)
{
    __shared__ float red[8][NP][64];
    int lane = threadIdx.x & 63;
    int w = threadIdx.x >> 6;
    int b = blockIdx.x * 64 + lane;

#pragma unroll 1
    for (int rep = 0; rep < REP_FIN; ++rep) {
        float s[NP];
#pragma unroll
        for (int k = 0; k < NP; ++k) s[k] = 0.f;
#pragma unroll
        for (int i = 0; i < 2; ++i) {
            const float* pt = ptl2 + (size_t)(w * 2 + i) * NP * NB + b;
#pragma unroll
            for (int k = 0; k < NP; ++k) s[k] += pt[(size_t)k * NB];
        }

        if (w >= 8) {
#pragma unroll
            for (int k = 0; k < NP; ++k) red[w - 8][k][lane] = s[k];
        }
        __syncthreads();
        if (w < 8) {
#pragma unroll
            for (int k = 0; k < NP; ++k) s[k] += red[w][k][lane];
        }
        __syncthreads();
        if (w >= 4 && w < 8) {
#pragma unroll
            for (int k = 0; k < NP; ++k) red[w - 4][k][lane] = s[k];
        }
        __syncthreads();
        if (w < 4) {
#pragma unroll
            for (int k = 0; k < NP; ++k) s[k] += red[w][k][lane];
        }
        __syncthreads();
        if (w >= 2 && w < 4) {
#pragma unroll
            for (int k = 0; k < NP; ++k) red[w - 2][k][lane] = s[k];
        }
        __syncthreads();
        if (w < 2) {
#pragma unroll
            for (int k = 0; k < NP; ++k) s[k] += red[w][k][lane];
        }
        __syncthreads();
        if (w == 1) {
#pragma unroll
            for (int k = 0; k < NP; ++k) red[0][k][lane] = s[k];
        }
        __syncthreads();
        if (w == 0) {
#pragma unroll
            for (int k = 0; k < NP; ++k) s[k] += red[0][k][lane];

            float* ob = out + (size_t)b * 21;
#pragma unroll
            for (int x = 0; x < 5; ++x) {
                float c = s[5 + x];
                ob[x] = (c > 0.f) ? (s[x] / c) : 0.f;
            }
            float invg = 1.f / s[26];
#pragma unroll
            for (int n = 0; n < 16; ++n) ob[5 + n] = s[10 + n] * invg;
        }
        __syncthreads();
    }
}

// ---------------------------------------------------------------------------
extern "C" void kernel_launch(void* const* d_in, const int* in_sizes, int n_in,
                              void* d_out, int out_size, void* d_ws, size_t ws_size,
                              hipStream_t stream)
{
    const float* d     = (const float*)d_in[0];
    const int*   idx   = (const int*)  d_in[1];
    const int*   cc    = (const int*)  d_in[2];
    const float* w_clc = (const float*)d_in[3];
    const float* b_clc = (const float*)d_in[4];
    const float* w1    = (const float*)d_in[5];
    const float* b1    = (const float*)d_in[6];
    const float* w2    = (const float*)d_in[7];
    const float* b2    = (const float*)d_in[8];
    float* out = (float*)d_out;

    unsigned short* Wf = (unsigned short*)d_ws;            // [2048][2048] bf16
    unsigned short* db = Wf + (size_t)NN2 * ND;            // [1024][2048] bf16
    float* ptl2 = (float*)(db + (size_t)NB * ND);          // [32][27][1024] f32

    prep_kernel<<<640, 1024, 0, stream>>>(idx, w_clc, w1, w2, d, Wf, db);
    fused_kernel<<<dim3(32, 16), 256, 0, stream>>>(db, Wf, b_clc, b1, b2, w2, cc, ptl2);
    finalize_kernel<<<16, 1024, 0, stream>>>(ptl2, out);
}

// Round 16
// 38.893 us; speedup vs baseline: 6.5636x; 6.5636x over previous
//
#include <hip/hip_runtime.h>

// Problem constants
#define NT 64
#define NF 1024
#define NB 1024
#define ND 2048
#define NTP 32
#define NN2 (NT * NTP)
#define NP 27
#define NW2ROW 1027
#define BK 64
#define BM 64
#define BN 64

typedef __attribute__((ext_vector_type(8))) short short8;
typedef __attribute__((ext_vector_type(4))) float f32x4;

static __device__ __forceinline__ unsigned short f2bf(float x) {
    unsigned u = __float_as_uint(x);
    unsigned r = (u + 0x7FFFu + ((u >> 16) & 1u)) >> 16;   // RNE
    return (unsigned short)r;
}

// ---------------------------------------------------------------------------
// prep v5 (j-range split, R14): grid 640 x 1024 threads.
// ---------------------------------------------------------------------------
__global__ __launch_bounds__(1024) void prep_kernel(
    const int* __restrict__ idx, const float* __restrict__ w_clc,
    const float* __restrict__ w1, const float* __restrict__ w2,
    const float* __restrict__ d, unsigned short* __restrict__ Wf,
    unsigned short* __restrict__ db)
{
    __shared__ __align__(16) float tile[21 * 256];   // 21,504 B
    int bid = blockIdx.x;
    int tid = threadIdx.x;

    if (bid < 512) {
        int t = bid >> 3, je = bid & 7;

        float4* tz = (float4*)tile;
        for (int i = tid; i < 1344; i += 1024) tz[i] = make_float4(0, 0, 0, 0);
        __syncthreads();

        {
            int f = tid;
            int j = idx[t * NF + f];
            if ((j >> 8) == je) {
                int jl = j & 255;
                float2 a = *(const float2*)&w_clc[(size_t)(t * NF + f) * 2];
                atomicAdd(&tile[0 * 256 + jl], a.x);
                atomicAdd(&tile[1 * 256 + jl], a.y);
                const float* p1 = &w1[(size_t)(t * NF + f) * 3];
                atomicAdd(&tile[2 * 256 + jl], p1[0]);
                atomicAdd(&tile[3 * 256 + jl], p1[1]);
                atomicAdd(&tile[4 * 256 + jl], p1[2]);
                const float* w2row = &w2[((size_t)t * NW2ROW + f) * 16];
                float4 q0 = *(const float4*)&w2row[0];
                float4 q1 = *(const float4*)&w2row[4];
                float4 q2 = *(const float4*)&w2row[8];
                float4 q3 = *(const float4*)&w2row[12];
                atomicAdd(&tile[ 5 * 256 + jl], q0.x);
                atomicAdd(&tile[ 6 * 256 + jl], q0.y);
                atomicAdd(&tile[ 7 * 256 + jl], q0.z);
                atomicAdd(&tile[ 8 * 256 + jl], q0.w);
                atomicAdd(&tile[ 9 * 256 + jl], q1.x);
                atomicAdd(&tile[10 * 256 + jl], q1.y);
                atomicAdd(&tile[11 * 256 + jl], q1.z);
                atomicAdd(&tile[12 * 256 + jl], q1.w);
                atomicAdd(&tile[13 * 256 + jl], q2.x);
                atomicAdd(&tile[14 * 256 + jl], q2.y);
                atomicAdd(&tile[15 * 256 + jl], q2.z);
                atomicAdd(&tile[16 * 256 + jl], q2.w);
                atomicAdd(&tile[17 * 256 + jl], q3.x);
                atomicAdd(&tile[18 * 256 + jl], q3.y);
                atomicAdd(&tile[19 * 256 + jl], q3.z);
                atomicAdd(&tile[20 * 256 + jl], q3.w);
            }
        }
        __syncthreads();

        for (int i = tid; i < 672; i += 1024) {
            int c = i >> 5, off = (i & 31) * 8;
            const float* tr = &tile[c * 256 + off];
            union { unsigned short u[8]; uint4 v; } pk;
#pragma unroll
            for (int e = 0; e < 8; ++e) pk.u[e] = f2bf(tr[e]);
            *(uint4*)&Wf[(size_t)(t * NTP + c) * ND + je * 256 + off] = pk.v;
        }
        uint4 z = make_uint4(0, 0, 0, 0);
        for (int i = tid; i < 352; i += 1024) {
            int c = 21 + (i >> 5), off = (i & 31) * 8;
            *(uint4*)&Wf[(size_t)(t * NTP + c) * ND + je * 256 + off] = z;
        }
    } else {
        int cb = bid - 512;
        int i16 = (cb * 1024 + tid) * 16;
#pragma unroll
        for (int h = 0; h < 2; ++h) {
            int i8 = i16 + h * 8;
            float4 a = *(const float4*)&d[i8];
            float4 b = *(const float4*)&d[i8 + 4];
            union { unsigned short u[8]; uint4 v; } pk;
            pk.u[0] = f2bf(a.x); pk.u[1] = f2bf(a.y); pk.u[2] = f2bf(a.z); pk.u[3] = f2bf(a.w);
            pk.u[4] = f2bf(b.x); pk.u[5] = f2bf(b.y); pk.u[6] = f2bf(b.z); pk.u[7] = f2bf(b.w);
            *(uint4*)&db[i8] = pk.v;
        }
    }
}

// ---------------------------------------------------------------------------
// Fused GEMM + epilogue — R14 geometry, NEW counted-vmcnt pipeline (T3/T4
// minimum form). Per kt: STAGE(next tile, +4 loads in flight) ->
// s_waitcnt vmcnt(4) (oldest 4 = CURRENT tile's loads done; next tile's 4
// stay in flight across the barrier) -> s_barrier (all waves see tile ready)
// -> ds_read + MFMA -> s_barrier (all waves done reading; WAR-safe for the
// overwrite two iterations later). sched_barrier(0) fences stop the
// scheduler hoisting ds_read above barrier1 / sinking STAGE above barrier2
// (rules #18/#21). This removes the per-kt vmcnt(0) drain that __syncthreads
// emitted (the ~500 cyc/kt exposed latency shown by R15's MfmaUtil=18%).
// ---------------------------------------------------------------------------
__global__ __launch_bounds__(256, 2) void fused_kernel(
    const unsigned short* __restrict__ A,    // db [1024][2048]
    const unsigned short* __restrict__ Bm,   // Wf [2048][2048]
    const float* __restrict__ b_clc, const float* __restrict__ b1,
    const float* __restrict__ b2, const float* __restrict__ w2,
    const int* __restrict__ cc, float* __restrict__ ptl2)
{
    __shared__ __align__(16) char smem[32768];
    unsigned short (*As)[BM][BK] = (unsigned short(*)[BM][BK])smem;             // 2x8 KB
    unsigned short (*Bs)[BN][BK] = (unsigned short(*)[BN][BK])(smem + 16384);   // 2x8 KB
    float* Cl  = (float*)smem;              // [64][65] = 16,640 B (alias)
    float* red = (float*)(smem + 16896);    // [27][64] = 6,912 B

    int tid = threadIdx.x;
    int lane = tid & 63;
    int wv = tid >> 6;
    int wr = wv & 1;
    int wq = wv >> 1;
    int nb = blockIdx.x;
    int mb = blockIdx.y;
    int m0 = mb * BM;
    int n0 = nb * BN;
    int r0 = lane & 15;
    int kq = lane >> 4;
    int sx = r0 & 7;
    int sl0 = ((0 * 4 + kq) ^ sx) * 8;
    int sl1 = ((1 * 4 + kq) ^ sx) * 8;

    f32x4 acc[2][2];
#pragma unroll
    for (int mi = 0; mi < 2; ++mi)
#pragma unroll
        for (int ni = 0; ni < 2; ++ni) acc[mi][ni] = (f32x4)0.f;

#define STAGE(buf, kt)                                                          \
    {                                                                           \
        size_t koff = (size_t)(kt) * BK;                                        \
        _Pragma("unroll")                                                       \
        for (int p = 0; p < 2; ++p) {                                           \
            int chunk = p * 256 + tid;                                          \
            int row = chunk >> 3, c = chunk & 7;                                \
            int csw = (c ^ (row & 7)) * 8;                                      \
            const unsigned short* ga = A + (size_t)(m0 + row) * ND + koff + csw;\
            __builtin_amdgcn_global_load_lds(                                   \
                (const __attribute__((address_space(1))) void*)ga,              \
                (__attribute__((address_space(3))) void*)&As[buf][row][c * 8],  \
                16, 0, 0);                                                      \
        }                                                                       \
        _Pragma("unroll")                                                       \
        for (int p = 0; p < 2; ++p) {                                           \
            int chunk = p * 256 + tid;                                          \
            int row = chunk >> 3, c = chunk & 7;                                \
            int csw = (c ^ (row & 7)) * 8;                                      \
            const unsigned short* gb = Bm + (size_t)(n0 + row) * ND + koff + csw;\
            __builtin_amdgcn_global_load_lds(                                   \
                (const __attribute__((address_space(1))) void*)gb,              \
                (__attribute__((address_space(3))) void*)&Bs[buf][row][c * 8],  \
                16, 0, 0);                                                      \
        }                                                                       \
    }

    STAGE(0, 0);                 // 4 loads in flight

    int cur = 0;
    for (int kt = 0; kt < 32; ++kt) {
        if (kt < 31) {
            STAGE(cur ^ 1, kt + 1);                              // 8 in flight
            asm volatile("s_waitcnt vmcnt(4)" ::: "memory");     // tile kt done
        } else {
            asm volatile("s_waitcnt vmcnt(0)" ::: "memory");
        }
        __builtin_amdgcn_s_barrier();            // (1) tile kt ready, all waves
        __builtin_amdgcn_sched_barrier(0);

        short8 af[2][2], bf[2][2];
#pragma unroll
        for (int mi = 0; mi < 2; ++mi) {
            af[mi][0] = *(const short8*)&As[cur][wr*32 + mi*16 + r0][sl0];
            af[mi][1] = *(const short8*)&As[cur][wr*32 + mi*16 + r0][sl1];
        }
#pragma unroll
        for (int ni = 0; ni < 2; ++ni) {
            bf[ni][0] = *(const short8*)&Bs[cur][wq*32 + ni*16 + r0][sl0];
            bf[ni][1] = *(const short8*)&Bs[cur][wq*32 + ni*16 + r0][sl1];
        }
#pragma unroll
        for (int ks = 0; ks < 2; ++ks)
#pragma unroll
            for (int mi = 0; mi < 2; ++mi)
#pragma unroll
                for (int ni = 0; ni < 2; ++ni)
                    acc[mi][ni] = __builtin_amdgcn_mfma_f32_16x16x32_bf16(
                        af[mi][ks], bf[ni][ks], acc[mi][ni], 0, 0, 0);

        __builtin_amdgcn_sched_barrier(0);
        __builtin_amdgcn_s_barrier();            // (2) reads of buf cur done
        __builtin_amdgcn_sched_barrier(0);
        cur ^= 1;
    }
#undef STAGE

    // C -> LDS. b = wr*32+mi*16+kq*4+q, n = wq*32+ni*16+r0. Stride 65.
#pragma unroll
    for (int mi = 0; mi < 2; ++mi)
#pragma unroll
        for (int ni = 0; ni < 2; ++ni) {
            int n = wq * 32 + ni * 16 + r0;
            int bl = wr * 32 + mi * 16 + kq * 4;
#pragma unroll
            for (int q = 0; q < 4; ++q)
                Cl[(bl + q) * 65 + n] = acc[mi][ni][q];
        }
    __syncthreads();

    // ---- epilogue: waves 0-1 = trees 0-1 (wave-uniform t), lane = b ----
    int tl = tid >> 6;
    int bl = lane;
    float s[NP];
#pragma unroll
    for (int k = 0; k < NP; ++k) s[k] = 0.f;

    if (tl < 2) {
        int t = nb * 2 + tl;

        float a21[21];
#pragma unroll
        for (int k = 0; k < 21; ++k) a21[k] = Cl[bl * 65 + tl * 32 + k];

        float L0 = a21[0] + b_clc[t * 2 + 0];
        float L1 = a21[1] + b_clc[t * 2 + 1];
        float mm = fmaxf(L0, L1);
        float e0 = __expf(L0 - mm), e1 = __expf(L1 - mm);
        float gate = e1 / (e0 + e1);

        float l1v[3];
        float m1 = -3.0e38f;
#pragma unroll
        for (int c = 0; c < 3; ++c) {
            l1v[c] = a21[2 + c] + b1[t * 3 + c];
            m1 = fmaxf(m1, l1v[c]);
        }
        float p1[3]; float S1 = 0.f;
#pragma unroll
        for (int c = 0; c < 3; ++c) { p1[c] = __expf(l1v[c] - m1); S1 += p1[c]; }
        float invS1g = gate / S1;

        float r0f = fmaxf(l1v[0], 0.f);
        float r1f = fmaxf(l1v[1], 0.f);
        float r2f = fmaxf(l1v[2], 0.f);

        const float* w2t = w2 + ((size_t)t * NW2ROW + NF) * 16;
        float l2[16]; float m2 = -3.0e38f;
#pragma unroll
        for (int nn = 0; nn < 16; ++nn) {
            float v = a21[5 + nn] + b2[t * 16 + nn];
            v = fmaf(r0f, w2t[nn], v);
            v = fmaf(r1f, w2t[16 + nn], v);
            v = fmaf(r2f, w2t[32 + nn], v);
            l2[nn] = v;
            m2 = fmaxf(m2, v);
        }
        float S2 = 0.f; float p2[16];
#pragma unroll
        for (int nn = 0; nn < 16; ++nn) { p2[nn] = __expf(l2[nn] - m2); S2 += p2[nn]; }
        float invS2g = gate * __frcp_rn(S2);

#pragma unroll
        for (int c = 0; c < 3; ++c) {
            int sl = cc[t * 3 + c];
            float pc = p1[c] * invS1g;
#pragma unroll
            for (int x = 0; x < 5; ++x) {
                if (sl == x) { s[x] += pc; s[5 + x] += gate; }
            }
        }
#pragma unroll
        for (int nn = 0; nn < 16; ++nn) s[10 + nn] += p2[nn] * invS2g;
        s[26] += gate;
    }

    if (tl == 1) {
#pragma unroll
        for (int k = 0; k < NP; ++k) red[k * 64 + bl] = s[k];
    }
    __syncthreads();
    if (tl != 0) return;

#pragma unroll
    for (int k = 0; k < NP; ++k) s[k] += red[k * 64 + bl];

    float* pt = ptl2 + (size_t)nb * NP * NB + m0 + bl;
#pragma unroll
    for (int k = 0; k < NP; ++k)
        pt[(size_t)k * NB] = s[k];
}

// ---------------------------------------------------------------------------
// Finalize (R14): grid 16 x 1024 threads; 4-phase LDS tree reduce.
// ---------------------------------------------------------------------------
__global__ __launch_bounds__(1024) void finalize_kernel(
    const float* __restrict__ ptl2, float* __restrict__ out)
{
    __shared__ float red[8][NP][64];
    int lane = threadIdx.x & 63;
    int w = threadIdx.x >> 6;
    int b = blockIdx.x * 64 + lane;

    float s[NP];
#pragma unroll
    for (int k = 0; k < NP; ++k) s[k] = 0.f;
#pragma unroll
    for (int i = 0; i < 2; ++i) {
        const float* pt = ptl2 + (size_t)(w * 2 + i) * NP * NB + b;
#pragma unroll
        for (int k = 0; k < NP; ++k) s[k] += pt[(size_t)k * NB];
    }

    if (w >= 8) {
#pragma unroll
        for (int k = 0; k < NP; ++k) red[w - 8][k][lane] = s[k];
    }
    __syncthreads();
    if (w < 8) {
#pragma unroll
        for (int k = 0; k < NP; ++k) s[k] += red[w][k][lane];
    }
    __syncthreads();
    if (w >= 4 && w < 8) {
#pragma unroll
        for (int k = 0; k < NP; ++k) red[w - 4][k][lane] = s[k];
    }
    __syncthreads();
    if (w < 4) {
#pragma unroll
        for (int k = 0; k < NP; ++k) s[k] += red[w][k][lane];
    }
    __syncthreads();
    if (w >= 2 && w < 4) {
#pragma unroll
        for (int k = 0; k < NP; ++k) red[w - 2][k][lane] = s[k];
    }
    __syncthreads();
    if (w < 2) {
#pragma unroll
        for (int k = 0; k < NP; ++k) s[k] += red[w][k][lane];
    }
    __syncthreads();
    if (w == 1) {
#pragma unroll
        for (int k = 0; k < NP; ++k) red[0][k][lane] = s[k];
    }
    __syncthreads();
    if (w != 0) return;
#pragma unroll
    for (int k = 0; k < NP; ++k) s[k] += red[0][k][lane];

    float* ob = out + (size_t)b * 21;
#pragma unroll
    for (int x = 0; x < 5; ++x) {
        float c = s[5 + x];
        ob[x] = (c > 0.f) ? (s[x] / c) : 0.f;
    }
    float invg = 1.f / s[26];
#pragma unroll
    for (int n = 0; n < 16; ++n) ob[5 + n] = s[10 + n] * invg;
}

// ---------------------------------------------------------------------------
extern "C" void kernel_launch(void* const* d_in, const int* in_sizes, int n_in,
                              void* d_out, int out_size, void* d_ws, size_t ws_size,
                              hipStream_t stream)
{
    const float* d     = (const float*)d_in[0];
    const int*   idx   = (const int*)  d_in[1];
    const int*   cc    = (const int*)  d_in[2];
    const float* w_clc = (const float*)d_in[3];
    const float* b_clc = (const float*)d_in[4];
    const float* w1    = (const float*)d_in[5];
    const float* b1    = (const float*)d_in[6];
    const float* w2    = (const float*)d_in[7];
    const float* b2    = (const float*)d_in[8];
    float* out = (float*)d_out;

    unsigned short* Wf = (unsigned short*)d_ws;            // [2048][2048] bf16
    unsigned short* db = Wf + (size_t)NN2 * ND;            // [1024][2048] bf16
    float* ptl2 = (float*)(db + (size_t)NB * ND);          // [32][27][1024] f32

    prep_kernel<<<640, 1024, 0, stream>>>(idx, w_clc, w1, w2, d, Wf, db);
    fused_kernel<<<dim3(32, 16), 256, 0, stream>>>(db, Wf, b_clc, b1, b2, w2, cc, ptl2);
    finalize_kernel<<<16, 1024, 0, stream>>>(ptl2, out);
}